// Round 2
// 600.070 us; speedup vs baseline: 1.0008x; 1.0008x over previous
//
#include <hip/hip_runtime.h>

#define ROWS  16384
#define PTOT  1048576
#define NTOTF 1048576.0f
#define EPSF  1e-5f
#define NREP  16                 // stats replication factor (atomic decontention)

typedef _Float16 half8  __attribute__((ext_vector_type(8)));   // MFMA A/B frag (4 VGPR)
typedef _Float16 half2v __attribute__((ext_vector_type(2)));
typedef __fp16   fp16x2 __attribute__((ext_vector_type(2)));   // cvt_pkrtz result type
typedef __attribute__((ext_vector_type(4))) float floatx4;     // MFMA C/D frag
typedef float f32x4 __attribute__((ext_vector_type(4)));
typedef f32x4 f32x4u __attribute__((aligned(4)));              // 4B-aligned vector load

union H8 { half8 v8; half2v v2[4]; };
union PK2 { fp16x2 p; half2v h; unsigned int u; };

__device__ __forceinline__ half2v cvt2(float lo, float hi) {
    PK2 k; k.p = __builtin_amdgcn_cvt_pkrtz(lo, hi); return k.h;
}
__device__ __forceinline__ unsigned int cvt2u(float lo, float hi) {
    PK2 k; k.p = __builtin_amdgcn_cvt_pkrtz(lo, hi); return k.u;
}
__device__ __forceinline__ float relu_f(float x) { return x > 0.f ? x : 0.f; }

__device__ __forceinline__ half8 h8zero() {
    half8 z = {(_Float16)0.f, (_Float16)0.f, (_Float16)0.f, (_Float16)0.f,
               (_Float16)0.f, (_Float16)0.f, (_Float16)0.f, (_Float16)0.f};
    return z;
}

// packed BN + ReLU: v_pk_fma_f16 + v_pk_max_f16
__device__ __forceinline__ half2v bn2(half2v h, half2v a, half2v b) {
    half2v z = {(_Float16)0.f, (_Float16)0.f};
    return __builtin_elementwise_max((half2v)(h * a + b), z);
}

// ---------------------------------------------------------------------------
// K1: conv0  X[P][67] fp32 -> H[P][64] fp16.  Operand-swapped MFMA:
// A = w0 (m=outch, persistent), B = X positions (n=pos), K=67 as 2 full
// k-steps + tail fragment (cols 64..66, quad0 only; loaded via float4 at
// col 63, elem 0 discarded -> always in bounds).  No LDS staging, no
// barriers in the main loop; direct 8B stores (C row=channel!).
// Bias folded into MFMA C-init.  All f32->f16 via v_cvt_pkrtz (1 instr / 2).
// ---------------------------------------------------------------------------
__global__ __launch_bounds__(256) void k_conv0(
    const float* __restrict__ X, const float* __restrict__ w0,
    const float* __restrict__ b0, _Float16* __restrict__ H,
    float* __restrict__ stats)
{
    __shared__ float sred[64], s2red[64];
    const int tid  = threadIdx.x;
    const int lane = tid & 63;
    const int wid  = tid >> 6;
    const int ln15 = lane & 15;
    const int quad = lane >> 4;
    const int pbase = blockIdx.x * 256 + wid * 64;

    if (tid < 64) { sred[tid] = 0.f; s2red[tid] = 0.f; }
    __syncthreads();

    // A-fragments: weights. m = mt*16+ln15, k = kh*32+quad*8+j (+ tail frag)
    half8 afr[4][3];
    floatx4 bias[4];
#pragma unroll
    for (int mt = 0; mt < 4; ++mt) {
        const float* wr = w0 + (size_t)(mt * 16 + ln15) * 67;
#pragma unroll
        for (int kh = 0; kh < 2; ++kh) {
            f32x4u wa = *reinterpret_cast<const f32x4u*>(wr + kh * 32 + quad * 8);
            f32x4u wb = *reinterpret_cast<const f32x4u*>(wr + kh * 32 + quad * 8 + 4);
            H8 t;
            t.v2[0] = cvt2(wa[0], wa[1]);
            t.v2[1] = cvt2(wa[2], wa[3]);
            t.v2[2] = cvt2(wb[0], wb[1]);
            t.v2[3] = cvt2(wb[2], wb[3]);
            afr[mt][kh] = t.v8;
        }
        H8 t; t.v8 = h8zero();
        if (quad == 0) {
            f32x4u tv = *reinterpret_cast<const f32x4u*>(wr + 63);  // cols 63..66
            t.v2[0] = cvt2(tv[1], tv[2]);
            t.v2[1] = cvt2(tv[3], 0.f);
        }
        afr[mt][2] = t.v8;
        bias[mt] = *reinterpret_cast<const floatx4*>(b0 + mt * 16 + quad * 4);
    }

    float s[4][4] = {}, s2[4][4] = {};
#pragma unroll 2
    for (int nt = 0; nt < 4; ++nt) {
        const int pos = pbase + nt * 16 + ln15;
        const float* xr = X + (size_t)pos * 67;
        // B-fragments: n = ln15 (this position), k = kh*32+quad*8+j
        H8 B0, B1, BT;
        {
            f32x4u xa = *reinterpret_cast<const f32x4u*>(xr + quad * 8);
            f32x4u xb = *reinterpret_cast<const f32x4u*>(xr + quad * 8 + 4);
            f32x4u xc = *reinterpret_cast<const f32x4u*>(xr + 32 + quad * 8);
            f32x4u xd = *reinterpret_cast<const f32x4u*>(xr + 32 + quad * 8 + 4);
            B0.v2[0] = cvt2(xa[0], xa[1]);
            B0.v2[1] = cvt2(xa[2], xa[3]);
            B0.v2[2] = cvt2(xb[0], xb[1]);
            B0.v2[3] = cvt2(xb[2], xb[3]);
            B1.v2[0] = cvt2(xc[0], xc[1]);
            B1.v2[1] = cvt2(xc[2], xc[3]);
            B1.v2[2] = cvt2(xd[0], xd[1]);
            B1.v2[3] = cvt2(xd[2], xd[3]);
            BT.v8 = h8zero();
            if (quad == 0) {
                f32x4u tv = *reinterpret_cast<const f32x4u*>(xr + 63);
                BT.v2[0] = cvt2(tv[1], tv[2]);
                BT.v2[1] = cvt2(tv[3], 0.f);
            }
        }
#pragma unroll
        for (int mt = 0; mt < 4; ++mt) {
            floatx4 c = bias[mt];   // bias constant along cols -> C-init
            c = __builtin_amdgcn_mfma_f32_16x16x32_f16(afr[mt][0], B0.v8, c, 0, 0, 0);
            c = __builtin_amdgcn_mfma_f32_16x16x32_f16(afr[mt][1], B1.v8, c, 0, 0, 0);
            c = __builtin_amdgcn_mfma_f32_16x16x32_f16(afr[mt][2], BT.v8, c, 0, 0, 0);
            // C layout: row (=channel in tile) = quad*4+rg, col (=position) = ln15
            s[mt][0] += c[0]; s2[mt][0] += c[0] * c[0];
            s[mt][1] += c[1]; s2[mt][1] += c[1] * c[1];
            s[mt][2] += c[2]; s2[mt][2] += c[2] * c[2];
            s[mt][3] += c[3]; s2[mt][3] += c[3] * c[3];
            uint2 o;
            o.x = cvt2u(c[0], c[1]);
            o.y = cvt2u(c[2], c[3]);
            *reinterpret_cast<uint2*>(&H[(size_t)pos * 64 + mt * 16 + quad * 4]) = o;
        }
    }
    // stats: sum over positions = over ln15 lanes
#pragma unroll
    for (int mt = 0; mt < 4; ++mt)
#pragma unroll
        for (int rg = 0; rg < 4; ++rg) {
            s[mt][rg]  += __shfl_xor(s[mt][rg], 1, 64);  s[mt][rg]  += __shfl_xor(s[mt][rg], 2, 64);
            s[mt][rg]  += __shfl_xor(s[mt][rg], 4, 64);  s[mt][rg]  += __shfl_xor(s[mt][rg], 8, 64);
            s2[mt][rg] += __shfl_xor(s2[mt][rg], 1, 64); s2[mt][rg] += __shfl_xor(s2[mt][rg], 2, 64);
            s2[mt][rg] += __shfl_xor(s2[mt][rg], 4, 64); s2[mt][rg] += __shfl_xor(s2[mt][rg], 8, 64);
        }
    if (ln15 == 0) {
#pragma unroll
        for (int mt = 0; mt < 4; ++mt)
#pragma unroll
            for (int rg = 0; rg < 4; ++rg) {
                atomicAdd(&sred[mt * 16 + quad * 4 + rg], s[mt][rg]);
                atomicAdd(&s2red[mt * 16 + quad * 4 + rg], s2[mt][rg]);
            }
    }
    __syncthreads();
    const int rep = (blockIdx.x & (NREP - 1)) * 512;
    if (tid < 64) {
        unsafeAtomicAdd(&stats[rep + tid], sred[tid]);
        unsafeAtomicAdd(&stats[rep + 64 + tid], s2red[tid]);
    }
}

// ---------------------------------------------------------------------------
// K2: conv1 64->64. Same operand-swapped, barrier-free structure; BN0+relu
// applied fully packed (v_pk_fma_f16 + v_pk_max_f16) on fp16 fragments --
// zero unpack/repack, result feeds MFMA directly. In-place H via two
// restrict pointers (per-tile loads strictly precede same-tile stores by
// data dependence; tiles are address-disjoint).
// ---------------------------------------------------------------------------
__global__ __launch_bounds__(256) void k_conv1(
    const _Float16* __restrict__ Hin, _Float16* __restrict__ Hout,
    const float* __restrict__ w1, const float* __restrict__ b1,
    const float* __restrict__ g0, const float* __restrict__ be0,
    float* __restrict__ stats)
{
    __shared__ float als[64], bls[64], sred[64], s2red[64];
    const int tid  = threadIdx.x;
    const int lane = tid & 63;
    const int wid  = tid >> 6;
    const int ln15 = lane & 15;
    const int quad = lane >> 4;
    const int pbase = blockIdx.x * 256 + wid * 64;

    if (tid < 64) {
        float ssum = 0.f, qsum = 0.f;
#pragma unroll
        for (int r = 0; r < NREP; ++r) { ssum += stats[r * 512 + tid]; qsum += stats[r * 512 + 64 + tid]; }
        const float mean = ssum * (1.f / NTOTF);
        const float var  = qsum * (1.f / NTOTF) - mean * mean;
        const float a    = g0[tid] / sqrtf(var + EPSF);
        als[tid] = a; bls[tid] = be0[tid] - mean * a;
        sred[tid] = 0.f; s2red[tid] = 0.f;
    }
    __syncthreads();

    // per-lane packed BN coeffs for input channels k = kh*32 + quad*8 + j
    half2v a2[8], b2[8];
#pragma unroll
    for (int kh = 0; kh < 2; ++kh)
#pragma unroll
        for (int j2 = 0; j2 < 4; ++j2) {
            const int c0 = kh * 32 + quad * 8 + 2 * j2;
            half2v av = {(_Float16)als[c0], (_Float16)als[c0 + 1]};
            half2v bv = {(_Float16)bls[c0], (_Float16)bls[c0 + 1]};
            a2[kh * 4 + j2] = av; b2[kh * 4 + j2] = bv;
        }

    half8 afr[4][2];
    floatx4 bias[4];
#pragma unroll
    for (int mt = 0; mt < 4; ++mt) {
        const float* wr = w1 + (size_t)(mt * 16 + ln15) * 64;
#pragma unroll
        for (int kh = 0; kh < 2; ++kh) {
            f32x4 wa = *reinterpret_cast<const f32x4*>(wr + kh * 32 + quad * 8);
            f32x4 wb = *reinterpret_cast<const f32x4*>(wr + kh * 32 + quad * 8 + 4);
            H8 t;
            t.v2[0] = cvt2(wa[0], wa[1]);
            t.v2[1] = cvt2(wa[2], wa[3]);
            t.v2[2] = cvt2(wb[0], wb[1]);
            t.v2[3] = cvt2(wb[2], wb[3]);
            afr[mt][kh] = t.v8;
        }
        bias[mt] = *reinterpret_cast<const floatx4*>(b1 + mt * 16 + quad * 4);
    }

    float s[4][4] = {}, s2[4][4] = {};
#pragma unroll 2
    for (int nt = 0; nt < 4; ++nt) {
        const int pos = pbase + nt * 16 + ln15;
        H8 r0, r1;
        r0.v8 = *reinterpret_cast<const half8*>(&Hin[(size_t)pos * 64 + quad * 8]);
        r1.v8 = *reinterpret_cast<const half8*>(&Hin[(size_t)pos * 64 + 32 + quad * 8]);
        H8 f0, f1;
#pragma unroll
        for (int j2 = 0; j2 < 4; ++j2) {
            f0.v2[j2] = bn2(r0.v2[j2], a2[j2], b2[j2]);
            f1.v2[j2] = bn2(r1.v2[j2], a2[4 + j2], b2[4 + j2]);
        }
#pragma unroll
        for (int mt = 0; mt < 4; ++mt) {
            floatx4 c = bias[mt];
            c = __builtin_amdgcn_mfma_f32_16x16x32_f16(afr[mt][0], f0.v8, c, 0, 0, 0);
            c = __builtin_amdgcn_mfma_f32_16x16x32_f16(afr[mt][1], f1.v8, c, 0, 0, 0);
            s[mt][0] += c[0]; s2[mt][0] += c[0] * c[0];
            s[mt][1] += c[1]; s2[mt][1] += c[1] * c[1];
            s[mt][2] += c[2]; s2[mt][2] += c[2] * c[2];
            s[mt][3] += c[3]; s2[mt][3] += c[3] * c[3];
            uint2 o;
            o.x = cvt2u(c[0], c[1]);
            o.y = cvt2u(c[2], c[3]);
            *reinterpret_cast<uint2*>(&Hout[(size_t)pos * 64 + mt * 16 + quad * 4]) = o;
        }
    }
#pragma unroll
    for (int mt = 0; mt < 4; ++mt)
#pragma unroll
        for (int rg = 0; rg < 4; ++rg) {
            s[mt][rg]  += __shfl_xor(s[mt][rg], 1, 64);  s[mt][rg]  += __shfl_xor(s[mt][rg], 2, 64);
            s[mt][rg]  += __shfl_xor(s[mt][rg], 4, 64);  s[mt][rg]  += __shfl_xor(s[mt][rg], 8, 64);
            s2[mt][rg] += __shfl_xor(s2[mt][rg], 1, 64); s2[mt][rg] += __shfl_xor(s2[mt][rg], 2, 64);
            s2[mt][rg] += __shfl_xor(s2[mt][rg], 4, 64); s2[mt][rg] += __shfl_xor(s2[mt][rg], 8, 64);
        }
    if (ln15 == 0) {
#pragma unroll
        for (int mt = 0; mt < 4; ++mt)
#pragma unroll
            for (int rg = 0; rg < 4; ++rg) {
                atomicAdd(&sred[mt * 16 + quad * 4 + rg], s[mt][rg]);
                atomicAdd(&s2red[mt * 16 + quad * 4 + rg], s2[mt][rg]);
            }
    }
    __syncthreads();
    const int rep = (blockIdx.x & (NREP - 1)) * 512;
    if (tid < 64) {
        unsafeAtomicAdd(&stats[rep + 128 + tid], sred[tid]);
        unsafeAtomicAdd(&stats[rep + 192 + tid], s2red[tid]);
    }
}

// ---------------------------------------------------------------------------
// K3: conv2 64->128, A = data orientation (max over positions stays
// in-register/2-shfl). Packed BN1+relu in fp16; max/min monotone-BN trick;
// bias folded into MFMA C-init; stats replicated.
// ---------------------------------------------------------------------------
__global__ __launch_bounds__(256) void k_conv2(
    const _Float16* __restrict__ H, const float* __restrict__ w2,
    const float* __restrict__ b2c, const float* __restrict__ g1,
    const float* __restrict__ be1, float* __restrict__ rowmax,
    float* __restrict__ rowmin, float* __restrict__ stats)
{
    __shared__ float als[64], bls[64], sred[128], s2red[128];
    const int tid  = threadIdx.x;
    const int lane = tid & 63;
    const int wid  = tid >> 6;
    const int ln15 = lane & 15;
    const int quad = lane >> 4;
    const int r0   = blockIdx.x * 4;

    if (tid < 64) {
        float ssum = 0.f, qsum = 0.f;
#pragma unroll
        for (int r = 0; r < NREP; ++r) { ssum += stats[r * 512 + 128 + tid]; qsum += stats[r * 512 + 192 + tid]; }
        const float mean = ssum * (1.f / NTOTF);
        const float var  = qsum * (1.f / NTOTF) - mean * mean;
        const float a    = g1[tid] / sqrtf(var + EPSF);
        als[tid] = a; bls[tid] = be1[tid] - mean * a;
    }
    if (tid < 128) { sred[tid] = 0.f; s2red[tid] = 0.f; }
    __syncthreads();

    half2v a2[8], b2[8];
#pragma unroll
    for (int kh = 0; kh < 2; ++kh)
#pragma unroll
        for (int j2 = 0; j2 < 4; ++j2) {
            const int c0 = kh * 32 + quad * 8 + 2 * j2;
            half2v av = {(_Float16)als[c0], (_Float16)als[c0 + 1]};
            half2v bv = {(_Float16)bls[c0], (_Float16)bls[c0 + 1]};
            a2[kh * 4 + j2] = av; b2[kh * 4 + j2] = bv;
        }

    const int chHalf = (wid & 1) * 64;
    half8 bfr[8];
    float biasn[4];
#pragma unroll
    for (int nt = 0; nt < 4; ++nt) {
        const int n = chHalf + nt * 16 + ln15;
        biasn[nt] = b2c[n];
#pragma unroll
        for (int kh = 0; kh < 2; ++kh) {
            f32x4 wa = *reinterpret_cast<const f32x4*>(&w2[(size_t)n * 64 + kh * 32 + quad * 8]);
            f32x4 wb = *reinterpret_cast<const f32x4*>(&w2[(size_t)n * 64 + kh * 32 + quad * 8 + 4]);
            H8 t;
            t.v2[0] = cvt2(wa[0], wa[1]);
            t.v2[1] = cvt2(wa[2], wa[3]);
            t.v2[2] = cvt2(wb[0], wb[1]);
            t.v2[3] = cvt2(wb[2], wb[3]);
            bfr[nt * 2 + kh] = t.v8;
        }
    }

    float s[4] = {0, 0, 0, 0}, s2[4] = {0, 0, 0, 0};
    for (int rr = 0; rr < 2; ++rr) {
        const int prow = r0 + (wid >> 1) * 2 + rr;
        float mx[4] = {-3.4e38f, -3.4e38f, -3.4e38f, -3.4e38f};
        float mn[4] = {3.4e38f, 3.4e38f, 3.4e38f, 3.4e38f};
#pragma unroll 2
        for (int mt = 0; mt < 4; ++mt) {
            const size_t rowb = (size_t)(prow * 64 + mt * 16 + ln15) * 64;
            H8 r0f, r1f;
            r0f.v8 = *reinterpret_cast<const half8*>(&H[rowb + quad * 8]);
            r1f.v8 = *reinterpret_cast<const half8*>(&H[rowb + 32 + quad * 8]);
            H8 f0, f1;
#pragma unroll
            for (int j2 = 0; j2 < 4; ++j2) {
                f0.v2[j2] = bn2(r0f.v2[j2], a2[j2], b2[j2]);
                f1.v2[j2] = bn2(r1f.v2[j2], a2[4 + j2], b2[4 + j2]);
            }
#pragma unroll
            for (int nt = 0; nt < 4; ++nt) {
                floatx4 a = {biasn[nt], biasn[nt], biasn[nt], biasn[nt]};
                a = __builtin_amdgcn_mfma_f32_16x16x32_f16(f0.v8, bfr[nt * 2 + 0], a, 0, 0, 0);
                a = __builtin_amdgcn_mfma_f32_16x16x32_f16(f1.v8, bfr[nt * 2 + 1], a, 0, 0, 0);
#pragma unroll
                for (int rg = 0; rg < 4; ++rg) {
                    const float h = a[rg];
                    mx[nt] = fmaxf(mx[nt], h);
                    mn[nt] = fminf(mn[nt], h);
                    s[nt] += h; s2[nt] += h * h;
                }
            }
        }
#pragma unroll
        for (int nt = 0; nt < 4; ++nt) {
            mx[nt] = fmaxf(mx[nt], __shfl_xor(mx[nt], 16, 64));
            mx[nt] = fmaxf(mx[nt], __shfl_xor(mx[nt], 32, 64));
            mn[nt] = fminf(mn[nt], __shfl_xor(mn[nt], 16, 64));
            mn[nt] = fminf(mn[nt], __shfl_xor(mn[nt], 32, 64));
        }
        if (lane < 16) {
#pragma unroll
            for (int nt = 0; nt < 4; ++nt) {
                rowmax[(size_t)prow * 128 + chHalf + nt * 16 + lane] = mx[nt];
                rowmin[(size_t)prow * 128 + chHalf + nt * 16 + lane] = mn[nt];
            }
        }
    }
#pragma unroll
    for (int nt = 0; nt < 4; ++nt) {
        s[nt]  += __shfl_xor(s[nt], 16, 64);  s[nt]  += __shfl_xor(s[nt], 32, 64);
        s2[nt] += __shfl_xor(s2[nt], 16, 64); s2[nt] += __shfl_xor(s2[nt], 32, 64);
    }
    if (lane < 16) {
#pragma unroll
        for (int nt = 0; nt < 4; ++nt) {
            atomicAdd(&sred[chHalf + nt * 16 + ln15], s[nt]);
            atomicAdd(&s2red[chHalf + nt * 16 + ln15], s2[nt]);
        }
    }
    __syncthreads();
    const int rep = (blockIdx.x & (NREP - 1)) * 512;
    if (tid < 128) {
        unsafeAtomicAdd(&stats[rep + 256 + tid], sred[tid]);
        unsafeAtomicAdd(&stats[rep + 384 + tid], s2red[tid]);
    }
}

// ---------------------------------------------------------------------------
// K4: finalize BN2 + epilogue
// ---------------------------------------------------------------------------
__global__ __launch_bounds__(256) void k_out(
    const float* __restrict__ rowmax, const float* __restrict__ rowmin,
    const float* __restrict__ g2, const float* __restrict__ be2,
    const float* __restrict__ stats, float* __restrict__ out)
{
    __shared__ float als[128], bls[128];
    const int tid = threadIdx.x;
    if (tid < 128) {
        float ssum = 0.f, qsum = 0.f;
#pragma unroll
        for (int r = 0; r < NREP; ++r) { ssum += stats[r * 512 + 256 + tid]; qsum += stats[r * 512 + 384 + tid]; }
        const float mean = ssum * (1.f / NTOTF);
        const float var  = qsum * (1.f / NTOTF) - mean * mean;
        const float a    = g2[tid] / sqrtf(var + EPSF);
        als[tid] = a; bls[tid] = be2[tid] - mean * a;
    }
    __syncthreads();
    const int idx = blockIdx.x * 256 + tid;
    const int o = idx & 127;
    const float a = als[o];
    const float v = (a > 0.f) ? rowmax[idx] : rowmin[idx];
    out[idx] = relu_f(a * v + bls[o]);
}

// ---------------------------------------------------------------------------
extern "C" void kernel_launch(void* const* d_in, const int* in_sizes, int n_in,
                              void* d_out, int out_size, void* d_ws, size_t ws_size,
                              hipStream_t stream)
{
    (void)in_sizes; (void)n_in; (void)out_size; (void)ws_size;
    const float* X   = (const float*)d_in[0];
    const float* w0  = (const float*)d_in[1];
    const float* b0  = (const float*)d_in[2];
    const float* g0  = (const float*)d_in[3];
    const float* be0 = (const float*)d_in[4];
    const float* w1  = (const float*)d_in[5];
    const float* b1  = (const float*)d_in[6];
    const float* g1  = (const float*)d_in[7];
    const float* be1 = (const float*)d_in[8];
    const float* w2  = (const float*)d_in[9];
    const float* b2  = (const float*)d_in[10];
    const float* g2  = (const float*)d_in[11];
    const float* be2 = (const float*)d_in[12];
    float* out = (float*)d_out;

    char* ws = (char*)d_ws;
    _Float16* H = (_Float16*)ws;                             // 134,217,728 B
    float* rowmax = (float*)(ws + 134217728);                // 8,388,608 B
    float* rowmin = (float*)(ws + 134217728 + 8388608);      // 8,388,608 B
    float* stats  = (float*)(ws + 134217728 + 2 * 8388608);  // NREP*512 floats

    hipMemsetAsync(stats, 0, NREP * 512 * sizeof(float), stream);
    hipLaunchKernelGGL(k_conv0, dim3(PTOT / 256), dim3(256), 0, stream, X, w0, b0, H, stats);
    hipLaunchKernelGGL(k_conv1, dim3(PTOT / 256), dim3(256), 0, stream, H, H, w1, b1, g0, be0, stats);
    hipLaunchKernelGGL(k_conv2, dim3(ROWS / 4), dim3(256), 0, stream, H, w2, b2, g1, be1, rowmax, rowmin, stats);
    hipLaunchKernelGGL(k_out, dim3(ROWS * 128 / 256), dim3(256), 0, stream, rowmax, rowmin, g2, be2, stats, out);
}